// Round 1
// baseline (156.317 us; speedup 1.0000x reference)
//
#include <hip/hip_runtime.h>
#include <hip/hip_bf16.h>

constexpr int S = 256;
constexpr int D = 768;

// Stage 1: per-batch Gram matrix G = X * X^T in fp32.
// Grid: (4, 4, 16) -> blockIdx.x = 64-col tile, blockIdx.y = 64-row tile,
//       blockIdx.z = batch*2 + khalf (K split in two 384-wide halves).
// Block: 256 threads, each computes a 4x4 micro-tile.
__global__ __launch_bounds__(256) void gram_kernel(const float* __restrict__ X,
                                                   float* __restrict__ G) {
    const int batch = blockIdx.z >> 1;
    const int khalf = blockIdx.z & 1;
    const int k_base = khalf * (D / 2);
    const float* Xb = X + (size_t)batch * S * D;
    float* Gb = G + ((size_t)khalf * 8 + batch) * S * S;
    const int tI = blockIdx.y * 64;
    const int tJ = blockIdx.x * 64;

    __shared__ float As[64][17];
    __shared__ float Bs[64][17];

    const int t  = threadIdx.x;
    const int tx = t & 15;        // micro-tile col group
    const int ty = t >> 4;        // micro-tile row group
    const int lk  = t & 15;       // staging: k within 16-wide K tile
    const int lr0 = t >> 4;       // staging: base row

    float acc[4][4] = {};

    for (int k0 = 0; k0 < D / 2; k0 += 16) {
#pragma unroll
        for (int r = 0; r < 4; ++r) {
            const int row = lr0 + 16 * r;
            As[row][lk] = Xb[(size_t)(tI + row) * D + k_base + k0 + lk];
            Bs[row][lk] = Xb[(size_t)(tJ + row) * D + k_base + k0 + lk];
        }
        __syncthreads();
#pragma unroll
        for (int kk = 0; kk < 16; ++kk) {
            float a[4], b[4];
#pragma unroll
            for (int r = 0; r < 4; ++r) a[r] = As[ty * 4 + r][kk];
#pragma unroll
            for (int r = 0; r < 4; ++r) b[r] = Bs[tx * 4 + r][kk];
#pragma unroll
            for (int i = 0; i < 4; ++i)
#pragma unroll
                for (int j = 0; j < 4; ++j)
                    acc[i][j] = fmaf(a[i], b[j], acc[i][j]);
        }
        __syncthreads();
    }

#pragma unroll
    for (int i = 0; i < 4; ++i)
#pragma unroll
        for (int j = 0; j < 4; ++j)
            Gb[(size_t)(tI + ty * 4 + i) * S + (tJ + tx * 4 + j)] = acc[i][j];
}

// Stage 2: per-batch (grid = 8 blocks, 256 threads).
// Thread b decides visibility of node b from node 0, then the block computes
// h = sum_s w_s * x_s, logits = h @ W, and log_softmax.
__global__ __launch_bounds__(256) void vis_kernel(const float* __restrict__ X,
                                                  const float* __restrict__ G,
                                                  const float* __restrict__ Wm,
                                                  float* __restrict__ out) {
    const int batch = blockIdx.x;
    const float* Xb = X + (size_t)batch * S * D;
    const float* G0 = G + (size_t)batch * S * S;
    const float* G1 = G + (size_t)(8 + batch) * S * S;
    const int b = threadIdx.x;

    __shared__ float wsh[S];
    __shared__ float hsh[D];
    __shared__ float lsh[4];

    // g_k = <x_k, x_b> = G[k][b] (full matrix stored, symmetric in exact math;
    // we read the column so loads coalesce across threads b).
    const float gb = G0[(size_t)b * S + b] + G1[(size_t)b * S + b];
    const float g0 = G0[b] + G1[b];

    bool vis = (b >= 1);
    for (int c = 1; c <= S - 2; ++c) {
        const float gc = G0[(size_t)c * S + b] + G1[(size_t)c * S + b];
        if (c < b) {
            // mirror reference order: d_b + ((y0 - y_b) * (b - c)) / b
            const float line = gb + ((g0 - gb) * (float)(b - c)) / (float)b;
            if (gc >= line) vis = false;
        }
    }
    wsh[b] = vis ? 1.0f : 0.0f;
    __syncthreads();

    // h[d] for d = b, b+256, b+512 (coalesced across threads).
    float h0 = 0.f, h1 = 0.f, h2 = 0.f;
    for (int s = 1; s < S; ++s) {
        if (wsh[s] != 0.0f) {   // block-uniform branch
            const float* xs = Xb + (size_t)s * D;
            h0 += xs[b];
            h1 += xs[b + 256];
            h2 += xs[b + 512];
        }
    }
    hsh[b] = h0;
    hsh[b + 256] = h1;
    hsh[b + 512] = h2;
    __syncthreads();

    // logits: wave k computes logit k via 12-chunk dot + shuffle reduce.
    const int wave = b >> 6;
    const int lane = b & 63;
    float sum = 0.f;
#pragma unroll
    for (int i = 0; i < 12; ++i) {
        const int dd = lane + 64 * i;
        sum = fmaf(hsh[dd], Wm[dd * 4 + wave], sum);
    }
#pragma unroll
    for (int off = 32; off > 0; off >>= 1) sum += __shfl_down(sum, off);
    if (lane == 0) lsh[wave] = sum;
    __syncthreads();

    if (b == 0) {
        const float l0 = lsh[0], l1 = lsh[1], l2 = lsh[2], l3 = lsh[3];
        const float m = fmaxf(fmaxf(l0, l1), fmaxf(l2, l3));
        const float lse = logf(expf(l0 - m) + expf(l1 - m) + expf(l2 - m) + expf(l3 - m));
        out[batch * 4 + 0] = l0 - m - lse;
        out[batch * 4 + 1] = l1 - m - lse;
        out[batch * 4 + 2] = l2 - m - lse;
        out[batch * 4 + 3] = l3 - m - lse;
    }
}

extern "C" void kernel_launch(void* const* d_in, const int* in_sizes, int n_in,
                              void* d_out, int out_size, void* d_ws, size_t ws_size,
                              hipStream_t stream) {
    const float* X  = (const float*)d_in[0];   // [8, 256, 768] fp32
    const float* Wm = (const float*)d_in[1];   // [768, 4] fp32
    float* out = (float*)d_out;                // [8, 4] fp32
    float* G   = (float*)d_ws;                 // 2 halves x 8 x 256 x 256 fp32 = 4 MB

    dim3 g1(4, 4, 16);
    gram_kernel<<<g1, 256, 0, stream>>>(X, G);
    vis_kernel<<<8, 256, 0, stream>>>(X, G, Wm, out);
}

// Round 2
// 35.995 us; speedup vs baseline: 4.3427x; 4.3427x over previous
//
#include <hip/hip_runtime.h>
#include <hip/hip_bf16.h>

constexpr int S = 256;
constexpr int D = 768;

// Stage 1: per-batch Gram matrix G = X * X^T in fp32, two K-halves (slices).
// Grid (4,4,16): x = 64-col tile, y = 64-row tile, z = batch*2 + khalf.
// LDS stored [k][row] so fragments are contiguous -> ds_read_b128.
// Accumulation order identical to the round-1 validated kernel (bit-exact G,
// and G[i][j] == G[j][i] bitwise since fma(a,b,c)==fma(b,a,c)).
__global__ __launch_bounds__(256) void gram_kernel(const float* __restrict__ X,
                                                   float* __restrict__ G) {
    const int batch = blockIdx.z >> 1;
    const int khalf = blockIdx.z & 1;
    const int k_base = khalf * (D / 2);
    const float* Xb = X + (size_t)batch * S * D;
    float* Gb = G + ((size_t)khalf * 8 + batch) * S * S;
    const int tI = blockIdx.y * 64;
    const int tJ = blockIdx.x * 64;

    __shared__ float As[16][68];   // [k][row], stride 68*4B = 272B (16B aligned)
    __shared__ float Bs[16][68];

    const int t   = threadIdx.x;
    const int tx  = t & 15;        // micro-tile col group
    const int ty  = t >> 4;        // micro-tile row group
    const int lk  = t & 15;        // staging: k within 16-wide K tile
    const int lr0 = t >> 4;        // staging: base row

    float acc[4][4] = {};

    for (int k0 = 0; k0 < D / 2; k0 += 16) {
#pragma unroll
        for (int r = 0; r < 4; ++r) {
            const int row = lr0 + 16 * r;
            As[lk][row] = Xb[(size_t)(tI + row) * D + k_base + k0 + lk];
            Bs[lk][row] = Xb[(size_t)(tJ + row) * D + k_base + k0 + lk];
        }
        __syncthreads();
#pragma unroll
        for (int kk = 0; kk < 16; ++kk) {
            const float4 av = *(const float4*)&As[kk][ty * 4];
            const float4 bv = *(const float4*)&Bs[kk][tx * 4];
            const float a[4] = {av.x, av.y, av.z, av.w};
            const float b[4] = {bv.x, bv.y, bv.z, bv.w};
#pragma unroll
            for (int i = 0; i < 4; ++i)
#pragma unroll
                for (int j = 0; j < 4; ++j)
                    acc[i][j] = fmaf(a[i], b[j], acc[i][j]);
        }
        __syncthreads();
    }

#pragma unroll
    for (int i = 0; i < 4; ++i)
#pragma unroll
        for (int j = 0; j < 4; ++j)
            Gb[(size_t)(tI + ty * 4 + i) * S + (tJ + tx * 4 + j)] = acc[i][j];
}

// P = X @ W  (per batch: [256 x 768] @ [768 x 4]).
// Grid (64, 8), 256 threads; one wave per sequence position s.
__global__ __launch_bounds__(256) void xw_kernel(const float* __restrict__ X,
                                                 const float* __restrict__ Wm,
                                                 float* __restrict__ P) {
    const int batch = blockIdx.y;
    const int wave  = threadIdx.x >> 6;
    const int lane  = threadIdx.x & 63;
    const int s     = blockIdx.x * 4 + wave;
    const float* xs = X + ((size_t)batch * S + s) * D;

    float a0 = 0.f, a1 = 0.f, a2 = 0.f, a3 = 0.f;
#pragma unroll
    for (int i = 0; i < 3; ++i) {
        const int d0 = (lane + 64 * i) * 4;
        const float4 xv = *(const float4*)(xs + d0);
        const float xf[4] = {xv.x, xv.y, xv.z, xv.w};
#pragma unroll
        for (int j = 0; j < 4; ++j) {
            const float4 wv = *(const float4*)(Wm + (size_t)(d0 + j) * 4);
            a0 = fmaf(xf[j], wv.x, a0);
            a1 = fmaf(xf[j], wv.y, a1);
            a2 = fmaf(xf[j], wv.z, a2);
            a3 = fmaf(xf[j], wv.w, a3);
        }
    }
#pragma unroll
    for (int off = 32; off; off >>= 1) {
        a0 += __shfl_xor(a0, off);
        a1 += __shfl_xor(a1, off);
        a2 += __shfl_xor(a2, off);
        a3 += __shfl_xor(a3, off);
    }
    if (lane == 0) {
        float4 o = {a0, a1, a2, a3};
        *(float4*)(P + ((size_t)batch * S + s) * 4) = o;
    }
}

// Visibility weights w[batch][b] for node 0's row. Grid (64, 8), one wave per b.
// Reads ROW b of G (== column b bitwise, G symmetric) -> coalesced.
__global__ __launch_bounds__(256) void vis_kernel(const float* __restrict__ G,
                                                  float* __restrict__ w) {
    const int batch = blockIdx.y;
    const int wave  = threadIdx.x >> 6;
    const int lane  = threadIdx.x & 63;
    const int b     = blockIdx.x * 4 + wave;

    const float* r0 = G + ((size_t)batch * S + b) * S;
    const float* r1 = r0 + (size_t)8 * S * S;

    const float gb = r0[b] + r1[b];
    const float g0 = r0[0] + r1[0];
    const float denom = (b > 0) ? (float)b : 1.0f;

    bool blocked = false;
#pragma unroll
    for (int i = 0; i < 4; ++i) {
        const int c = lane + 64 * i;
        const float gc = r0[c] + r1[c];
        // same formula/rounding structure as the validated round-1 kernel
        const float line = gb + ((g0 - gb) * (float)(b - c)) / denom;
        if (c >= 1 && c < b && gc >= line) blocked = true;
    }
    const bool anyb = __any(blocked);
    if (lane == 0) w[batch * S + b] = (b >= 1 && !anyb) ? 1.0f : 0.0f;
}

// logits_k = sum_s w_s * P[s][k]; then log_softmax. Grid 8 blocks, wave k per logit.
__global__ __launch_bounds__(256) void head_kernel(const float* __restrict__ P,
                                                   const float* __restrict__ w,
                                                   float* __restrict__ out) {
    const int batch = blockIdx.x;
    const int k     = threadIdx.x >> 6;
    const int lane  = threadIdx.x & 63;

    float sum = 0.f;
#pragma unroll
    for (int i = 0; i < 4; ++i) {
        const int s = lane + 64 * i;
        sum = fmaf(w[batch * S + s], P[((size_t)batch * S + s) * 4 + k], sum);
    }
#pragma unroll
    for (int off = 32; off; off >>= 1) sum += __shfl_xor(sum, off);

    __shared__ float lsh[4];
    if (lane == 0) lsh[k] = sum;
    __syncthreads();

    if (threadIdx.x == 0) {
        const float l0 = lsh[0], l1 = lsh[1], l2 = lsh[2], l3 = lsh[3];
        const float m = fmaxf(fmaxf(l0, l1), fmaxf(l2, l3));
        const float lse = logf(expf(l0 - m) + expf(l1 - m) + expf(l2 - m) + expf(l3 - m));
        out[batch * 4 + 0] = l0 - m - lse;
        out[batch * 4 + 1] = l1 - m - lse;
        out[batch * 4 + 2] = l2 - m - lse;
        out[batch * 4 + 3] = l3 - m - lse;
    }
}

extern "C" void kernel_launch(void* const* d_in, const int* in_sizes, int n_in,
                              void* d_out, int out_size, void* d_ws, size_t ws_size,
                              hipStream_t stream) {
    const float* X  = (const float*)d_in[0];   // [8, 256, 768] fp32
    const float* Wm = (const float*)d_in[1];   // [768, 4] fp32
    float* out = (float*)d_out;                // [8, 4] fp32

    float* ws = (float*)d_ws;
    float* P  = ws;                            // 8*256*4   = 8192 floats
    float* wv = ws + 8192;                     // 8*256     = 2048 floats
    float* G  = ws + 8192 + 2048;              // 2*8*256*256 floats (~4 MB)

    gram_kernel<<<dim3(4, 4, 16), 256, 0, stream>>>(X, G);
    xw_kernel  <<<dim3(64, 8),    256, 0, stream>>>(X, Wm, P);
    vis_kernel <<<dim3(64, 8),    256, 0, stream>>>(G, wv);
    head_kernel<<<8,              256, 0, stream>>>(P, wv, out);
}

// Round 3
// 26.620 us; speedup vs baseline: 5.8721x; 1.3522x over previous
//
#include <hip/hip_runtime.h>
#include <hip/hip_bf16.h>

constexpr int S = 256;
constexpr int D = 768;
constexpr int KSLICES = 4;
constexpr int KS = D / KSLICES;   // 192 = 12 k-tiles of 16

// Stage 1: per-batch Gram matrix G = X * X^T in fp32, 4 K-slices.
// Grid (4,4,32): x = 64-col tile, y = 64-row tile, z = batch*4 + kq.
// 512 blocks -> 2 blocks/CU -> 2 waves/SIMD (TLP), register-prefetched staging.
// Each slice is bitwise symmetric: fixed k accumulation order, fmaf(a,b,c)==fmaf(b,a,c).
__global__ __launch_bounds__(256) void gram_kernel(const float* __restrict__ X,
                                                   float* __restrict__ G) {
    const int batch  = blockIdx.z >> 2;
    const int kq     = blockIdx.z & 3;
    const int k_base = kq * KS;
    const float* Xb = X + (size_t)batch * S * D;
    float* Gb = G + ((size_t)kq * 8 + batch) * S * S;
    const int tI = blockIdx.y * 64;
    const int tJ = blockIdx.x * 64;

    __shared__ float As[16][68];   // [k][row]; fragment reads are ds_read_b128
    __shared__ float Bs[16][68];

    const int t    = threadIdx.x;
    const int tx   = t & 15;       // micro-tile col group
    const int ty   = t >> 4;       // micro-tile row group
    const int srow = t >> 2;       // staging row 0..63
    const int skq  = (t & 3) * 4;  // staging k offset 0,4,8,12 (float4)

    const float* pa = Xb + (size_t)(tI + srow) * D + k_base + skq;
    const float* pb = Xb + (size_t)(tJ + srow) * D + k_base + skq;

    float4 va = *(const float4*)pa;
    float4 vb = *(const float4*)pb;

    float acc[4][4] = {};

    for (int k0 = 0; k0 < KS; k0 += 16) {
        __syncthreads();           // previous compute done before overwrite
        As[skq + 0][srow] = va.x; As[skq + 1][srow] = va.y;
        As[skq + 2][srow] = va.z; As[skq + 3][srow] = va.w;
        Bs[skq + 0][srow] = vb.x; Bs[skq + 1][srow] = vb.y;
        Bs[skq + 2][srow] = vb.z; Bs[skq + 3][srow] = vb.w;
        if (k0 + 16 < KS) {        // prefetch next tile; latency hides under FMAs
            va = *(const float4*)(pa + k0 + 16);
            vb = *(const float4*)(pb + k0 + 16);
        }
        __syncthreads();
#pragma unroll
        for (int kk = 0; kk < 16; ++kk) {
            const float4 av = *(const float4*)&As[kk][ty * 4];
            const float4 bv = *(const float4*)&Bs[kk][tx * 4];
            const float a[4] = {av.x, av.y, av.z, av.w};
            const float b[4] = {bv.x, bv.y, bv.z, bv.w};
#pragma unroll
            for (int i = 0; i < 4; ++i)
#pragma unroll
                for (int j = 0; j < 4; ++j)
                    acc[i][j] = fmaf(a[i], b[j], acc[i][j]);
        }
    }

#pragma unroll
    for (int i = 0; i < 4; ++i)
#pragma unroll
        for (int j = 0; j < 4; ++j)
            Gb[(size_t)(tI + ty * 4 + i) * S + (tJ + tx * 4 + j)] = acc[i][j];
}

// Stage 2 (fused): per wave, position m = blockIdx.x*4 + wave:
//   P[m][:] = x_m @ W   and   w[m] = visibility of node m from node 0.
// Grid (64, 8), 256 threads. G slice rows read coalesced (bitwise-symmetric slices).
__global__ __launch_bounds__(256) void visxw_kernel(const float* __restrict__ X,
                                                    const float* __restrict__ Wm,
                                                    const float* __restrict__ G,
                                                    float* __restrict__ P,
                                                    float* __restrict__ w) {
    const int batch = blockIdx.y;
    const int wave  = threadIdx.x >> 6;
    const int lane  = threadIdx.x & 63;
    const int b     = blockIdx.x * 4 + wave;

    // ---- P[b][:] = x_b @ W ----
    const float* xs = X + ((size_t)batch * S + b) * D;
    float a0 = 0.f, a1 = 0.f, a2 = 0.f, a3 = 0.f;
#pragma unroll
    for (int i = 0; i < 3; ++i) {
        const int d0 = (lane + 64 * i) * 4;
        const float4 xv = *(const float4*)(xs + d0);
        const float xf[4] = {xv.x, xv.y, xv.z, xv.w};
#pragma unroll
        for (int j = 0; j < 4; ++j) {
            const float4 wv = *(const float4*)(Wm + (size_t)(d0 + j) * 4);
            a0 = fmaf(xf[j], wv.x, a0);
            a1 = fmaf(xf[j], wv.y, a1);
            a2 = fmaf(xf[j], wv.z, a2);
            a3 = fmaf(xf[j], wv.w, a3);
        }
    }

    // ---- visibility of b from 0 ----
    const float* r0 = G + ((size_t)batch * S + b) * S;   // slice 0, row b
    const size_t SL = (size_t)8 * S * S;                 // slice stride

    const float gb = r0[b] + r0[b + SL] + r0[b + 2 * SL] + r0[b + 3 * SL];
    const float g0 = r0[0] + r0[0 + SL] + r0[0 + 2 * SL] + r0[0 + 3 * SL];
    const float denom = (b > 0) ? (float)b : 1.0f;

    bool blocked = false;
#pragma unroll
    for (int i = 0; i < 4; ++i) {
        const int c = lane + 64 * i;
        const float gc = r0[c] + r0[c + SL] + r0[c + 2 * SL] + r0[c + 3 * SL];
        const float line = gb + ((g0 - gb) * (float)(b - c)) / denom;
        if (c >= 1 && c < b && gc >= line) blocked = true;
    }
    const bool anyb = __any(blocked);

#pragma unroll
    for (int off = 32; off; off >>= 1) {
        a0 += __shfl_xor(a0, off);
        a1 += __shfl_xor(a1, off);
        a2 += __shfl_xor(a2, off);
        a3 += __shfl_xor(a3, off);
    }
    if (lane == 0) {
        float4 o = {a0, a1, a2, a3};
        *(float4*)(P + ((size_t)batch * S + b) * 4) = o;
        w[batch * S + b] = (b >= 1 && !anyb) ? 1.0f : 0.0f;
    }
}

// logits_k = sum_s w_s * P[s][k]; then log_softmax. Grid 8 blocks, wave k per logit.
__global__ __launch_bounds__(256) void head_kernel(const float* __restrict__ P,
                                                   const float* __restrict__ w,
                                                   float* __restrict__ out) {
    const int batch = blockIdx.x;
    const int k     = threadIdx.x >> 6;
    const int lane  = threadIdx.x & 63;

    float sum = 0.f;
#pragma unroll
    for (int i = 0; i < 4; ++i) {
        const int s = lane + 64 * i;
        sum = fmaf(w[batch * S + s], P[((size_t)batch * S + s) * 4 + k], sum);
    }
#pragma unroll
    for (int off = 32; off; off >>= 1) sum += __shfl_xor(sum, off);

    __shared__ float lsh[4];
    if (lane == 0) lsh[k] = sum;
    __syncthreads();

    if (threadIdx.x == 0) {
        const float l0 = lsh[0], l1 = lsh[1], l2 = lsh[2], l3 = lsh[3];
        const float m = fmaxf(fmaxf(l0, l1), fmaxf(l2, l3));
        const float lse = logf(expf(l0 - m) + expf(l1 - m) + expf(l2 - m) + expf(l3 - m));
        out[batch * 4 + 0] = l0 - m - lse;
        out[batch * 4 + 1] = l1 - m - lse;
        out[batch * 4 + 2] = l2 - m - lse;
        out[batch * 4 + 3] = l3 - m - lse;
    }
}

extern "C" void kernel_launch(void* const* d_in, const int* in_sizes, int n_in,
                              void* d_out, int out_size, void* d_ws, size_t ws_size,
                              hipStream_t stream) {
    const float* X  = (const float*)d_in[0];   // [8, 256, 768] fp32
    const float* Wm = (const float*)d_in[1];   // [768, 4] fp32
    float* out = (float*)d_out;                // [8, 4] fp32

    float* ws = (float*)d_ws;
    float* P  = ws;                            // 8*256*4 floats
    float* wv = ws + 8192;                     // 8*256 floats
    float* G  = ws + 8192 + 2048;              // 4 slices x 8 x 256 x 256 floats (8 MB)

    gram_kernel <<<dim3(4, 4, 32), 256, 0, stream>>>(X, G);
    visxw_kernel<<<dim3(64, 8),    256, 0, stream>>>(X, Wm, G, P, wv);
    head_kernel <<<8,              256, 0, stream>>>(P, wv, out);
}